// Round 1
// baseline (1221.395 us; speedup 1.0000x reference)
//
#include <hip/hip_runtime.h>
#include <hip/hip_bf16.h>
#include <math.h>

// Problem constants (from reference)
#define B_      8
#define D_      64
#define HW_     (512 * 512)
#define C_      19          // NUM_CLASSES
#define K_      18          // C_ - 1 (class 0 dropped)

constexpr int BLOCKS_PER_B = 128;
constexpr int PIX_PER_BLK  = HW_ / BLOCKS_PER_B;   // 2048
constexpr int THREADS      = 256;
constexpr int ACC_STRIDE   = 65;                   // pad: bank = (c*65+d)%32 = (c+d)%32

// ---------------------------------------------------------------------------
// Kernel 1: per-(b, pixel-chunk) masked class sums + counts -> global atomics
// ---------------------------------------------------------------------------
__global__ __launch_bounds__(THREADS)
void frc_accum(const float* __restrict__ feat,
               const int*   __restrict__ label,
               float*       __restrict__ gsums,    // [B][C][D]
               unsigned*    __restrict__ gcounts)  // [B][C]
{
    const int b    = blockIdx.y;
    const int pix0 = blockIdx.x * PIX_PER_BLK;
    const int t    = threadIdx.x;

    __shared__ float         acc[C_ * ACC_STRIDE];
    __shared__ unsigned      cnt_s[C_];
    __shared__ unsigned char lab_s[PIX_PER_BLK];

    for (int i = t; i < C_ * ACC_STRIDE; i += THREADS) acc[i] = 0.f;
    if (t < C_) cnt_s[t] = 0u;
    __syncthreads();

    // --- stage labels (int4 vectorized), remap 255->0, clamp for safety ---
    const int4* lp = reinterpret_cast<const int4*>(label + (size_t)b * HW_ + pix0);
    for (int i = t; i < PIX_PER_BLK / 4; i += THREADS) {
        int4 l4 = lp[i];
        int c0 = (l4.x == 255) ? 0 : l4.x;  if ((unsigned)c0 >= C_) c0 = 0;
        int c1 = (l4.y == 255) ? 0 : l4.y;  if ((unsigned)c1 >= C_) c1 = 0;
        int c2 = (l4.z == 255) ? 0 : l4.z;  if ((unsigned)c2 >= C_) c2 = 0;
        int c3 = (l4.w == 255) ? 0 : l4.w;  if ((unsigned)c3 >= C_) c3 = 0;
        lab_s[i * 4 + 0] = (unsigned char)c0;
        lab_s[i * 4 + 1] = (unsigned char)c1;
        lab_s[i * 4 + 2] = (unsigned char)c2;
        lab_s[i * 4 + 3] = (unsigned char)c3;
        atomicAdd(&cnt_s[c0], 1u);
        atomicAdd(&cnt_s[c1], 1u);
        atomicAdd(&cnt_s[c2], 1u);
        atomicAdd(&cnt_s[c3], 1u);
    }
    __syncthreads();

    // --- preload this thread's 8 pixel classes into registers ---
    // float4 iteration j handles pixels (t + j*256)*4 .. +3
    int myoff[2][4];
    #pragma unroll
    for (int j = 0; j < 2; ++j) {
        #pragma unroll
        for (int k = 0; k < 4; ++k) {
            int c = lab_s[(t + j * THREADS) * 4 + k];
            myoff[j][k] = c * ACC_STRIDE;   // pre-multiplied LDS offset
        }
    }

    // --- main streaming loop: d outer, float4 pixels inner ---
    const float* fb = feat + ((size_t)b * D_) * HW_ + pix0;
    for (int d = 0; d < D_; ++d) {
        const float4* fp = reinterpret_cast<const float4*>(fb + (size_t)d * HW_);
        #pragma unroll
        for (int j = 0; j < 2; ++j) {
            float4 v = fp[t + j * THREADS];
            atomicAdd(&acc[myoff[j][0] + d], v.x);
            atomicAdd(&acc[myoff[j][1] + d], v.y);
            atomicAdd(&acc[myoff[j][2] + d], v.z);
            atomicAdd(&acc[myoff[j][3] + d], v.w);
        }
    }
    __syncthreads();

    // --- flush block partials to global ---
    for (int i = t; i < C_ * D_; i += THREADS) {
        int c = i / D_, d = i % D_;
        atomicAdd(&gsums[((size_t)b * C_ + c) * D_ + d], acc[c * ACC_STRIDE + d]);
    }
    if (t < C_) atomicAdd(&gcounts[b * C_ + t], cnt_s[t]);
}

// ---------------------------------------------------------------------------
// Kernel 2: tiny epilogue -> scalar loss
// ---------------------------------------------------------------------------
__global__ __launch_bounds__(256)
void frc_finalize(const float*    __restrict__ gsums,    // [B][C][D]
                  const unsigned* __restrict__ gcounts,  // [B][C]
                  float*          __restrict__ out)
{
    __shared__ float emb[K_][D_];
    __shared__ float dots[K_][K_];
    __shared__ float sq[K_];
    __shared__ float rowloss[K_];
    const int t = threadIdx.x;

    // embeddings[k][d] = (sum_b sums[b][k+1][d] / (cnt[b][k+1]+eps)) / num[k+1]
    for (int idx = t; idx < K_ * D_; idx += 256) {
        int k = idx / D_, d = idx % D_, c = k + 1;
        float e = 0.f;
        int   num = 0;
        #pragma unroll
        for (int b = 0; b < B_; ++b) {
            unsigned cnt = gcounts[b * C_ + c];
            e   += gsums[((size_t)b * C_ + c) * D_ + d] / ((float)cnt + 1e-6f);
            num += (cnt > 0u) ? 1 : 0;
        }
        emb[k][d] = e / (float)num;
    }
    __syncthreads();

    // dots[i][j] = emb[i] . emb[j]
    for (int idx = t; idx < K_ * K_; idx += 256) {
        int i = idx / K_, j = idx % K_;
        float s = 0.f;
        #pragma unroll
        for (int d = 0; d < D_; ++d) s += emb[i][d] * emb[j][d];
        dots[i][j] = s;
    }
    __syncthreads();

    if (t < K_) sq[t] = dots[t][t];
    __syncthreads();

    // per-row: cos = dots/(sq_i*sq_j); log_softmax; -diag
    if (t < K_) {
        float crow[K_];
        float m = -INFINITY;
        #pragma unroll
        for (int j = 0; j < K_; ++j) {
            float c = dots[t][j] / (sq[t] * sq[j]);
            crow[j] = c;
            m = fmaxf(m, c);
        }
        float s = 0.f;
        #pragma unroll
        for (int j = 0; j < K_; ++j) s += expf(crow[j] - m);
        float lse = m + logf(s);
        rowloss[t] = -(crow[t] - lse);
    }
    __syncthreads();

    if (t == 0) {
        float L = 0.f;
        #pragma unroll
        for (int i = 0; i < K_; ++i) L += rowloss[i];
        out[0] = L / (float)K_;
    }
}

// ---------------------------------------------------------------------------
extern "C" void kernel_launch(void* const* d_in, const int* in_sizes, int n_in,
                              void* d_out, int out_size, void* d_ws, size_t ws_size,
                              hipStream_t stream)
{
    const float* feat  = (const float*)d_in[0];   // [8,64,512,512] f32
    const int*   label = (const int*)d_in[1];     // [8,1,512,512] i32
    float*       out   = (float*)d_out;           // scalar

    // workspace layout: sums [B*C*D] f32, counts [B*C] u32
    float*    gsums   = (float*)d_ws;
    unsigned* gcounts = (unsigned*)((char*)d_ws + (size_t)B_ * C_ * D_ * sizeof(float));
    size_t zero_bytes = (size_t)B_ * C_ * D_ * sizeof(float) + (size_t)B_ * C_ * sizeof(unsigned);

    hipMemsetAsync(d_ws, 0, zero_bytes, stream);

    dim3 grid(BLOCKS_PER_B, B_);
    frc_accum<<<grid, THREADS, 0, stream>>>(feat, label, gsums, gcounts);
    frc_finalize<<<1, 256, 0, stream>>>(gsums, gcounts, out);
}